// Round 2
// baseline (123.089 us; speedup 1.0000x reference)
//
#include <hip/hip_runtime.h>
#include <math.h>

namespace {
constexpr int B_ = 4, K_ = 8, W_ = 1024;
constexpr int N_ = 512 * 1024;          // pixels per image
constexpr int M_ = 128;                 // err histogram bins over [0,2]
constexpr int MP_ = M_ + 1;             // padded LDS row
constexpr int BK_ = B_ * K_;
constexpr int KM_ = K_ * M_;            // 1024 bins per hist-block partial

constexpr int HB_ = 1024;               // hist blocks
constexpr int HBPB_ = HB_ / B_;         // 256 per image
constexpr int HCH_ = N_ / HBPB_;        // 2048 pixels per block (2 float4 iters)
constexpr int SB_ = 1024;               // stats blocks
constexpr int SBPB_ = SB_ / B_;         // 256 per image
constexpr int SCH_ = N_ / SBPB_;        // 2048 pixels per block
constexpr int NSTAT = 41;               // interleaved k*5+{cnt,xm,ym,s,s2}, [40]=bg
constexpr int NHC_ = 4;                 // hist sub-copies (indexed by tid&3) — R11

// workspace layout (bytes)
constexpr size_t PART_BYTES = (size_t)HB_ * KM_ * 4;             // 4 MB
constexpr size_t SFG_OFF_B  = PART_BYTES;                        // 32*256 floats
constexpr size_t PSTAT_OFF_B = SFG_OFF_B + (size_t)BK_ * HBPB_ * 4;
constexpr size_t WSF_OFF_B  = PSTAT_OFF_B + (size_t)B_ * NSTAT * SBPB_ * 4;

// wsf float offsets (written by finalize, read by hist/lovasz)
constexpr int CNT_OFF  = 0;             // 32 per-(b,k) counts
constexpr int OBJF_OFF = 32;            // 4 per-image objf
constexpr int PRM_OFF  = 64;            // b*3 rows of K_: {cx, cy, sexp}
}

__device__ __forceinline__ float fsigmoid_(float x) { return 1.0f / (1.0f + __expf(-x)); }
__device__ __forceinline__ float ftanh_(float x) { return 1.0f - 2.0f / (__expf(2.0f * x) + 1.0f); }

// ---- Stage 1: per-instance stats partials; block 0 zeroes out[0] ----
// LAYOUT CONTRACT: pstat row r=b*NSTAT+st holds 256 block-partials at [r<<8 ..].
// st = k*5+{cnt,xm,ym,s,s2}, st=40 = bg seed^2 sum.
// NOTE: no min-waves __launch_bounds__ arg — 41 reg accumulators spill with it (R3).
__global__ __launch_bounds__(256) void stats_kernel(const float* __restrict__ pred,
                                                    const int* __restrict__ inst,
                                                    const int* __restrict__ lab,
                                                    float* __restrict__ pstat,
                                                    float* __restrict__ out) {
    int tid = threadIdx.x;
    if (blockIdx.x == 0 && tid == 0) out[0] = 0.0f;   // later dispatches atomicAdd
    int b = blockIdx.x >> 8;
    int blk = blockIdx.x & (SBPB_ - 1);
    int pix0 = blk * SCH_;

    const float* sigp = pred + ((long long)b * 4 + 2) * N_;
    const float* p3p  = pred + ((long long)b * 4 + 3) * N_;
    const int*   insp = inst + (long long)b * N_;
    const int*   labp = lab  + (long long)b * N_;

    float acc[NSTAT];
#pragma unroll
    for (int i = 0; i < NSTAT; i++) acc[i] = 0.0f;

#pragma unroll
    for (int it = 0; it < SCH_ / (256 * 4); it++) {
        int base = pix0 + (it * 256 + tid) * 4;
        float4 sg = *(const float4*)(sigp + base);
        float4 q3 = *(const float4*)(p3p + base);
        int4 in4 = *(const int4*)(insp + base);
        int4 lb4 = *(const int4*)(labp + base);
        float ss[4] = {sg.x, sg.y, sg.z, sg.w};
        float qq[4] = {q3.x, q3.y, q3.z, q3.w};
        int ii[4] = {in4.x, in4.y, in4.z, in4.w};
        int ll[4] = {lb4.x, lb4.y, lb4.z, lb4.w};
#pragma unroll
        for (int j = 0; j < 4; j++) {
            int pix = base + j;
            float xm = (float)(pix & (W_ - 1)) * (2.0f / 2047.0f);
            float ym = (float)(pix >> 10) * (1.0f / 1023.0f);
            float seed = fsigmoid_(qq[j]);
            if (ll[j] == 0) acc[40] += seed * seed;
            float s = ss[j];
#pragma unroll
            for (int k = 0; k < K_; k++) {
                float m = (ii[j] == k + 1) ? 1.0f : 0.0f;
                acc[k * 5]     += m;
                acc[k * 5 + 1] += m * xm;
                acc[k * 5 + 2] += m * ym;
                acc[k * 5 + 3] += m * s;
                acc[k * 5 + 4] += m * s * s;
            }
        }
    }
#pragma unroll
    for (int i = 0; i < NSTAT; i++) {
        float v = acc[i];
#pragma unroll
        for (int off = 32; off; off >>= 1) v += __shfl_down(v, off, 64);
        acc[i] = v;
    }
    __shared__ float xw[4][NSTAT];
    if ((tid & 63) == 0) {
        int w = tid >> 6;
#pragma unroll
        for (int i = 0; i < NSTAT; i++) xw[w][i] = acc[i];
    }
    __syncthreads();
    if (tid < NSTAT)
        pstat[((b * NSTAT + tid) << 8) + blk] =
            xw[0][tid] + xw[1][tid] + xw[2][tid] + xw[3][tid];
}

// ---- Stage 1.5 (R12): one block per image reduces pstat ONCE and publishes
// params. Replaces the per-hist-block prologue that re-read 42 KB x 1024
// blocks = 43 MB of L2 and serialized a dependent-load chain before pixel
// work. Also owns the var/objf/bg contribution to out.
__global__ __launch_bounds__(256) void finalize_kernel(const float* __restrict__ pstat,
                                                       float* __restrict__ wsf,
                                                       float* __restrict__ out) {
    __shared__ float sq[NSTAT][4];
    __shared__ float ssum[NSTAT];
    __shared__ float svar[K_];
    __shared__ int spres[K_];
    int tid = threadIdx.x;
    int b = blockIdx.x;

    if (tid < NSTAT * 4) {
        int row = tid >> 2, q = tid & 3;
        const float4* p = (const float4*)(pstat + ((size_t)(b * NSTAT + row) << 8)) + q * 16;
        float4 a = {0, 0, 0, 0};
#pragma unroll
        for (int j = 0; j < 16; j++) {
            float4 v = p[j];
            a.x += v.x; a.y += v.y; a.z += v.z; a.w += v.w;
        }
        sq[row][q] = (a.x + a.y) + (a.z + a.w);
    }
    __syncthreads();
    if (tid < NSTAT) ssum[tid] = (sq[tid][0] + sq[tid][1]) + (sq[tid][2] + sq[tid][3]);
    __syncthreads();
    if (tid < K_) {
        float counts = ssum[tid * 5];
        float cnt = fmaxf(counts, 1.0f);
        float smean = ssum[tid * 5 + 3] / cnt;
        wsf[PRM_OFF + (b * 3 + 0) * K_ + tid] = ssum[tid * 5 + 1] / cnt;   // cx
        wsf[PRM_OFF + (b * 3 + 1) * K_ + tid] = ssum[tid * 5 + 2] / cnt;   // cy
        wsf[PRM_OFF + (b * 3 + 2) * K_ + tid] = expf(10.0f * smean);       // sexp
        wsf[CNT_OFF + b * K_ + tid] = counts;
        svar[tid] = (counts > 0.0f) ? ssum[tid * 5 + 4] / cnt - smean * smean : 0.0f;
        spres[tid] = counts > 0.0f ? 1 : 0;
    }
    __syncthreads();
    if (tid == 0) {
        float np = 0.0f, vl = 0.0f;
#pragma unroll
        for (int k = 0; k < K_; k++) { np += (float)spres[k]; vl += svar[k]; }
        float objf = fmaxf(np, 1.0f);
        wsf[OBJF_OFF + b] = objf;
        atomicAdd(out, (10.0f * vl / objf + ssum[40] / (float)N_) * (1.0f / (float)B_));
    }
}

// ---- Stage 2: hist ----
// R11: histogram in NHC_=4 LDS sub-copies selected by tid&3.
// R12a: prologue is now 5 tiny wsf loads (finalize_kernel did the reduce).
// R12b: bin-0 bg fast path — t = sxp*d2 > 5.0 (> ln128=4.852, strict margin so
// binning is bit-identical) provably lands in bin 0 for bg; count in a
// register n0[k] and flush with ONE wave-reduced atomic per (wave,k).
// Removes the hottest same-address ds_atomic stream (bin 0) + its exp/cvt.
__global__ __launch_bounds__(256) void hist_kernel(const float* __restrict__ pred,
                                                   const int* __restrict__ inst,
                                                   const float* __restrict__ wsf,
                                                   unsigned int* __restrict__ partial,
                                                   float* __restrict__ sfgpart,
                                                   float* __restrict__ out) {
    __shared__ float prm[4][K_];        // cx, cy, sexp, counts
    __shared__ unsigned int hsh[NHC_][K_ * MP_];   // ~16.5 KB, 129-padded rows
    __shared__ float xfg[4][K_];

    int tid = threadIdx.x;
    int b = blockIdx.x >> 8;            // HBPB_ = 256 blocks per image
    int blk = blockIdx.x & (HBPB_ - 1);
    int pix0 = blk * HCH_;

    if (tid < K_) {
        prm[0][tid] = wsf[PRM_OFF + (b * 3 + 0) * K_ + tid];
        prm[1][tid] = wsf[PRM_OFF + (b * 3 + 1) * K_ + tid];
        prm[2][tid] = wsf[PRM_OFF + (b * 3 + 2) * K_ + tid];
        prm[3][tid] = wsf[CNT_OFF + b * K_ + tid];
    }
    for (int i = tid; i < NHC_ * K_ * MP_; i += 256) (&hsh[0][0])[i] = 0u;
    __syncthreads();

    float cx[K_], cy[K_], sxp[K_];
    bool prs[K_];
#pragma unroll
    for (int k = 0; k < K_; k++) {
        cx[k] = prm[0][k]; cy[k] = prm[1][k]; sxp[k] = prm[2][k];
        prs[k] = prm[3][k] > 0.0f;
    }
    unsigned int* hpriv = &hsh[tid & 3][0];

    const float* p0p = pred + ((long long)b * 4) * N_;
    const float* p1p = p0p + N_;
    const float* p3p = p0p + 3LL * N_;
    const int* insp = inst + (long long)b * N_;

    float sfg[K_];
    unsigned int n0[K_];
#pragma unroll
    for (int k = 0; k < K_; k++) { sfg[k] = 0.0f; n0[k] = 0u; }

#pragma unroll
    for (int it = 0; it < HCH_ / (256 * 4); it++) {   // 2 float4 iterations
        int base = pix0 + (it * 256 + tid) * 4;
        float4 a0 = *(const float4*)(p0p + base);
        float4 a1 = *(const float4*)(p1p + base);
        float4 a3 = *(const float4*)(p3p + base);
        int4 in4 = *(const int4*)(insp + base);
        float v0[4] = {a0.x, a0.y, a0.z, a0.w};
        float v1[4] = {a1.x, a1.y, a1.z, a1.w};
        float v3[4] = {a3.x, a3.y, a3.z, a3.w};
        int ii[4] = {in4.x, in4.y, in4.z, in4.w};
#pragma unroll
        for (int j = 0; j < 4; j++) {
            int pix = base + j;
            float sex = ftanh_(v0[j]) + (float)(pix & (W_ - 1)) * (2.0f / 2047.0f);
            float sey = ftanh_(v1[j]) + (float)(pix >> 10) * (1.0f / 1023.0f);
            float seed = fsigmoid_(v3[j]);
            int ins = ii[j];
#pragma unroll
            for (int k = 0; k < K_; k++) {
                if (prs[k]) {
                    float dx = sex - cx[k];
                    float dy = sey - cy[k];
                    float t = sxp[k] * (dx * dx + dy * dy);
                    bool fg = (ins == k + 1);
                    if (!fg && t > 5.0f) {
                        n0[k]++;                       // provably bin 0, bg
                    } else {
                        float dist = __expf(-t);
                        // err_bg=2d, err_fg=2-2d; bin=floor(err*(M/2)):
                        int ib = (int)fminf(128.0f * dist, 127.0f);
                        int bin = fg ? 127 - ib : ib;
                        atomicAdd(hpriv + (k * MP_ + bin), fg ? 0x10001u : 1u);
                        if (fg) { float d = seed - dist; sfg[k] += d * d; }
                    }
                }
            }
        }
    }
    // flush register bin-0 counts: wave-reduce, one atomic per (wave,k)
#pragma unroll
    for (int k = 0; k < K_; k++) {
        unsigned int v = n0[k];
#pragma unroll
        for (int off = 32; off; off >>= 1) v += __shfl_down(v, off, 64);
        if ((tid & 63) == 0 && v) atomicAdd(hpriv + k * MP_, v);
    }
    __syncthreads();

    unsigned int* gp = partial + (size_t)blockIdx.x * KM_;
    for (int i = tid; i < KM_; i += 256) {
        int r = (i >> 7) * MP_ + (i & (M_ - 1));
        gp[i] = hsh[0][r] + hsh[1][r] + hsh[2][r] + hsh[3][r];
    }

    // seed_fg: wave shfl reduce -> cross-wave LDS -> plain store
#pragma unroll
    for (int k = 0; k < K_; k++) {
        float v = sfg[k];
#pragma unroll
        for (int off = 32; off; off >>= 1) v += __shfl_down(v, off, 64);
        sfg[k] = v;
    }
    if ((tid & 63) == 0) {
        int w = tid >> 6;
#pragma unroll
        for (int k = 0; k < K_; k++) xfg[w][k] = sfg[k];
    }
    __syncthreads();
    if (tid < K_)
        sfgpart[(size_t)(b * K_ + tid) * HBPB_ + blk] =
            xfg[0][tid] + xfg[1][tid] + xfg[2][tid] + xfg[3][tid];
}

// ---- Stage 3: fused partial-reduce + Lovasz suffix scan + seed_fg + out add ----
// 32 blocks x 1024 threads: 8 groups x 128 bins; each group sums 32 partials.
// loss = binw*[0.5*J_0 + sum_{j>=1} J_j], J_j = 1-(p-F_j)/(p+R_j-F_j).
// R11: 128-bin suffix scan + Jaccard + reduce in wave 0 registers (u64-packed
// {n,f}, 2 bins/lane, 6 shfl steps); seed_fg reduce concurrent on waves 4-7.
__global__ __launch_bounds__(1024) void lovasz_kernel(const unsigned int* __restrict__ partial,
                                                      const float* __restrict__ sfgpart,
                                                      const float* __restrict__ wsf,
                                                      float* __restrict__ out) {
    int bk = blockIdx.x;
    int b = bk >> 3, k = bk & 7;
    int tid = threadIdx.x;
    int bin = tid & (M_ - 1), grp = tid >> 7;   // grp 0..7
    constexpr int PER = HBPB_ / 8;              // 32 partials per group

    const unsigned int* p = partial +
        (size_t)(b * HBPB_ + grp * PER) * KM_ + k * M_ + bin;
    unsigned int n = 0, f = 0;
#pragma unroll 8
    for (int j = 0; j < PER; j++) {             // coalesced: 128 lanes x 4B per j
        unsigned int v = p[(size_t)j * KM_];
        n += v & 0xffffu;
        f += v >> 16;
    }

    __shared__ unsigned int gn[8][M_], gf[8][M_];
    __shared__ float lovp;
    __shared__ float xs[4];
    gn[grp][bin] = n; gf[grp][bin] = f;
    __syncthreads();

    float pcnt = wsf[CNT_OFF + bk];
    float pp = fmaxf(pcnt, 1.0f);

    if (tid < 64) {
        // wave 0: lane l owns bins 2l and 2l+1. Pack n in hi32, f in lo32
        // (suffix sums < 2^31 each, so no cross-field carry).
        unsigned long long p0 = 0ull, p1 = 0ull;
#pragma unroll
        for (int g = 0; g < 8; g++) {
            uint2 vn = *(const uint2*)&gn[g][2 * tid];
            uint2 vf = *(const uint2*)&gf[g][2 * tid];
            p0 += ((unsigned long long)vn.x << 32) | (unsigned long long)vf.x;
            p1 += ((unsigned long long)vn.y << 32) | (unsigned long long)vf.y;
        }
        // inclusive suffix scan over lane pair-sums (Hillis-Steele, 6 steps)
        unsigned long long T = p0 + p1;
#pragma unroll
        for (int off = 1; off < 64; off <<= 1) {
            unsigned long long t = __shfl_down(T, off, 64);
            if (tid + off < 64) T += t;
        }
        unsigned long long S0 = T;          // suffix from bin 2l
        unsigned long long S1 = T - p0;     // suffix from bin 2l+1
        float acc;
        {
            unsigned int R = (unsigned int)(S0 >> 32), F = (unsigned int)S0;
            float J = (R == 0) ? 0.0f : (1.0f - (pp - (float)F) / (pp + (float)(R - F)));
            acc = (tid == 0 ? 0.5f : 1.0f) * J;
        }
        {
            unsigned int R = (unsigned int)(S1 >> 32), F = (unsigned int)S1;
            float J = (R == 0) ? 0.0f : (1.0f - (pp - (float)F) / (pp + (float)(R - F)));
            acc += J;
        }
#pragma unroll
        for (int off = 32; off; off >>= 1) acc += __shfl_down(acc, off, 64);
        if (tid == 0) lovp = acc;
    } else if (tid >= 256 && tid < 512) {
        // waves 4-7 (concurrent with wave 0): seed_fg total, 256 partials
        float sv = sfgpart[(size_t)bk * HBPB_ + (tid - 256)];
#pragma unroll
        for (int off = 32; off; off >>= 1) sv += __shfl_down(sv, off, 64);
        if ((tid & 63) == 0) xs[(tid - 256) >> 6] = sv;
    }
    __syncthreads();

    if (tid == 0 && pcnt > 0.0f) {
        float lov = lovp * (2.0f / (float)M_);
        float sfgt = (xs[0] + xs[1]) + (xs[2] + xs[3]);
        float objf = wsf[OBJF_OFF + b];
        atomicAdd(out, (lov / objf + sfgt / (float)N_) * (1.0f / (float)B_));
    }
}

extern "C" void kernel_launch(void* const* d_in, const int* in_sizes, int n_in,
                              void* d_out, int out_size, void* d_ws, size_t ws_size,
                              hipStream_t stream) {
    const float* pred = (const float*)d_in[0];
    const int* inst = (const int*)d_in[1];
    const int* lab = (const int*)d_in[2];
    float* out = (float*)d_out;

    unsigned int* partial = (unsigned int*)d_ws;
    float* sfgpart = (float*)((char*)d_ws + SFG_OFF_B);
    float* pstat = (float*)((char*)d_ws + PSTAT_OFF_B);
    float* wsf = (float*)((char*)d_ws + WSF_OFF_B);

    // 4 dispatches; no memset (stats zeroes out[0]; ws fully overwritten).
    // NOTE: cooperative single-dispatch fusion measured 2.6x WORSE (R10) —
    // grid.sync on gfx950 forces cross-XCD L2 writeback/invalidate (~100us/sync).
    stats_kernel<<<SB_, 256, 0, stream>>>(pred, inst, lab, pstat, out);
    finalize_kernel<<<B_, 256, 0, stream>>>(pstat, wsf, out);
    hist_kernel<<<HB_, 256, 0, stream>>>(pred, inst, wsf, partial, sfgpart, out);
    lovasz_kernel<<<BK_, 1024, 0, stream>>>(partial, sfgpart, wsf, out);
}

// Round 3
// 116.477 us; speedup vs baseline: 1.0568x; 1.0568x over previous
//
#include <hip/hip_runtime.h>
#include <math.h>

namespace {
constexpr int B_ = 4, K_ = 8, W_ = 1024;
constexpr int N_ = 512 * 1024;          // pixels per image
constexpr int M_ = 128;                 // err histogram bins over [0,2]
constexpr int MP_ = M_ + 1;             // padded LDS row
constexpr int BK_ = B_ * K_;
constexpr int KM_ = K_ * M_;            // 1024 bins per hist-block partial

constexpr int HB_ = 512;                // hist blocks (R13: 1024->512, halves
                                        // prologue aggregate + partial buffer)
constexpr int HBPB_ = HB_ / B_;         // 128 per image
constexpr int HCH_ = N_ / HBPB_;        // 4096 pixels per block (4 float4 iters)
constexpr int SB_ = 1024;               // stats blocks
constexpr int SBPB_ = SB_ / B_;         // 256 per image
constexpr int SCH_ = N_ / SBPB_;        // 2048 pixels per block
constexpr int NSTAT = 41;               // interleaved k*5+{cnt,xm,ym,s,s2}, [40]=bg
constexpr int NHC_ = 4;                 // hist sub-copies (indexed by tid&3) — R11

// workspace layout (bytes)
constexpr size_t PART_BYTES = (size_t)HB_ * KM_ * 4;             // 2 MB
constexpr size_t SFG_OFF_B  = PART_BYTES;                        // 32*128 floats
constexpr size_t PSTAT_OFF_B = SFG_OFF_B + (size_t)BK_ * HBPB_ * 4;
constexpr size_t WSF_OFF_B  = PSTAT_OFF_B + (size_t)B_ * NSTAT * SBPB_ * 4;

// wsf float offsets (written by hist blk==0 blocks, read by lovasz)
constexpr int CNT_OFF  = 0;             // 32 per-(b,k) counts
constexpr int OBJF_OFF = 32;            // 4 per-image objf
}

__device__ __forceinline__ float fsigmoid_(float x) { return 1.0f / (1.0f + __expf(-x)); }
__device__ __forceinline__ float ftanh_(float x) { return 1.0f - 2.0f / (__expf(2.0f * x) + 1.0f); }

// ---- Stage 1: per-instance stats partials; block 0 zeroes out[0] ----
// LAYOUT CONTRACT: pstat row r=b*NSTAT+st holds 256 block-partials at [r<<8 ..].
// st = k*5+{cnt,xm,ym,s,s2}, st=40 = bg seed^2 sum.
// NOTE: no min-waves __launch_bounds__ arg — 41 reg accumulators spill with it (R3).
__global__ __launch_bounds__(256) void stats_kernel(const float* __restrict__ pred,
                                                    const int* __restrict__ inst,
                                                    const int* __restrict__ lab,
                                                    float* __restrict__ pstat,
                                                    float* __restrict__ out) {
    int tid = threadIdx.x;
    if (blockIdx.x == 0 && tid == 0) out[0] = 0.0f;   // later dispatches atomicAdd
    int b = blockIdx.x >> 8;
    int blk = blockIdx.x & (SBPB_ - 1);
    int pix0 = blk * SCH_;

    const float* sigp = pred + ((long long)b * 4 + 2) * N_;
    const float* p3p  = pred + ((long long)b * 4 + 3) * N_;
    const int*   insp = inst + (long long)b * N_;
    const int*   labp = lab  + (long long)b * N_;

    float acc[NSTAT];
#pragma unroll
    for (int i = 0; i < NSTAT; i++) acc[i] = 0.0f;

#pragma unroll
    for (int it = 0; it < SCH_ / (256 * 4); it++) {
        int base = pix0 + (it * 256 + tid) * 4;
        float4 sg = *(const float4*)(sigp + base);
        float4 q3 = *(const float4*)(p3p + base);
        int4 in4 = *(const int4*)(insp + base);
        int4 lb4 = *(const int4*)(labp + base);
        float ss[4] = {sg.x, sg.y, sg.z, sg.w};
        float qq[4] = {q3.x, q3.y, q3.z, q3.w};
        int ii[4] = {in4.x, in4.y, in4.z, in4.w};
        int ll[4] = {lb4.x, lb4.y, lb4.z, lb4.w};
#pragma unroll
        for (int j = 0; j < 4; j++) {
            int pix = base + j;
            float xm = (float)(pix & (W_ - 1)) * (2.0f / 2047.0f);
            float ym = (float)(pix >> 10) * (1.0f / 1023.0f);
            float seed = fsigmoid_(qq[j]);
            if (ll[j] == 0) acc[40] += seed * seed;
            float s = ss[j];
#pragma unroll
            for (int k = 0; k < K_; k++) {
                float m = (ii[j] == k + 1) ? 1.0f : 0.0f;
                acc[k * 5]     += m;
                acc[k * 5 + 1] += m * xm;
                acc[k * 5 + 2] += m * ym;
                acc[k * 5 + 3] += m * s;
                acc[k * 5 + 4] += m * s * s;
            }
        }
    }
#pragma unroll
    for (int i = 0; i < NSTAT; i++) {
        float v = acc[i];
#pragma unroll
        for (int off = 32; off; off >>= 1) v += __shfl_down(v, off, 64);
        acc[i] = v;
    }
    __shared__ float xw[4][NSTAT];
    if ((tid & 63) == 0) {
        int w = tid >> 6;
#pragma unroll
        for (int i = 0; i < NSTAT; i++) xw[w][i] = acc[i];
    }
    __syncthreads();
    if (tid < NSTAT)
        pstat[((b * NSTAT + tid) << 8) + blk] =
            xw[0][tid] + xw[1][tid] + xw[2][tid] + xw[3][tid];
}

// ---- Stage 2: hist with inline finalize prologue ----
// Prologue: every block reduces its image's 41 pstat rows (L2-resident) to get
// cx,cy,sexp,counts. blk==0 blocks additionally write wsf counts/objf and
// atomicAdd the (10*var/objf + bg/N)/B loss terms into out.
// R11: histogram in NHC_=4 LDS sub-copies selected by tid&3 (copy stride 1032
// words = +8 banks). R12b fast path REVERTED (sexp~1 => t>5 never fires; the
// branch+registers were pure overhead). R13: 512 blocks of 4096 px — halves
// prologue aggregate, partial buffer, LDS zero/merge totals.
__global__ __launch_bounds__(256) void hist_kernel(const float* __restrict__ pred,
                                                   const int* __restrict__ inst,
                                                   const float* __restrict__ pstat,
                                                   float* __restrict__ wsf,
                                                   unsigned int* __restrict__ partial,
                                                   float* __restrict__ sfgpart,
                                                   float* __restrict__ out) {
    __shared__ float sq[NSTAT][4];
    __shared__ float ssum[NSTAT];
    __shared__ float prm[K_][4];        // cx, cy, sexp, counts
    __shared__ float svar[K_];
    __shared__ int spres[K_];
    __shared__ unsigned int hsh[NHC_][K_ * MP_];   // ~16.5 KB, 129-padded rows
    __shared__ float xfg[4][K_];

    int tid = threadIdx.x;
    int b = blockIdx.x >> 7;            // HBPB_ = 128 blocks per image
    int blk = blockIdx.x & (HBPB_ - 1);
    int pix0 = blk * HCH_;

    // ---- prologue: reduce pstat rows for this image ----
    if (tid < NSTAT * 4) {
        int row = tid >> 2, q = tid & 3;
        const float4* p = (const float4*)(pstat + ((size_t)(b * NSTAT + row) << 8)) + q * 16;
        float4 a = {0, 0, 0, 0};
#pragma unroll
        for (int j = 0; j < 16; j++) {
            float4 v = p[j];
            a.x += v.x; a.y += v.y; a.z += v.z; a.w += v.w;
        }
        sq[row][q] = (a.x + a.y) + (a.z + a.w);
    }
    for (int i = tid; i < NHC_ * K_ * MP_; i += 256) (&hsh[0][0])[i] = 0u;
    __syncthreads();
    if (tid < NSTAT) ssum[tid] = (sq[tid][0] + sq[tid][1]) + (sq[tid][2] + sq[tid][3]);
    __syncthreads();
    if (tid < K_) {
        float counts = ssum[tid * 5];
        float cnt = fmaxf(counts, 1.0f);
        float smean = ssum[tid * 5 + 3] / cnt;
        prm[tid][0] = ssum[tid * 5 + 1] / cnt;        // cx
        prm[tid][1] = ssum[tid * 5 + 2] / cnt;        // cy
        prm[tid][2] = expf(10.0f * smean);            // sexp (accurate)
        prm[tid][3] = counts;
        if (blk == 0) {
            svar[tid] = (counts > 0.0f) ? ssum[tid * 5 + 4] / cnt - smean * smean : 0.0f;
            spres[tid] = counts > 0.0f ? 1 : 0;
            wsf[CNT_OFF + b * K_ + tid] = counts;
        }
    }
    __syncthreads();
    if (blk == 0 && tid == 0) {                       // one block per image
        float np = 0.0f, vl = 0.0f;
#pragma unroll
        for (int k = 0; k < K_; k++) { np += (float)spres[k]; vl += svar[k]; }
        float objf = fmaxf(np, 1.0f);
        wsf[OBJF_OFF + b] = objf;
        atomicAdd(out, (10.0f * vl / objf + ssum[40] / (float)N_) * (1.0f / (float)B_));
    }

    float cx[K_], cy[K_], sxp[K_];
    bool prs[K_];
#pragma unroll
    for (int k = 0; k < K_; k++) {
        cx[k] = prm[k][0]; cy[k] = prm[k][1]; sxp[k] = prm[k][2];
        prs[k] = prm[k][3] > 0.0f;
    }
    unsigned int* hpriv = &hsh[tid & 3][0];

    const float* p0p = pred + ((long long)b * 4) * N_;
    const float* p1p = p0p + N_;
    const float* p3p = p0p + 3LL * N_;
    const int* insp = inst + (long long)b * N_;

    float sfg[K_];
#pragma unroll
    for (int k = 0; k < K_; k++) sfg[k] = 0.0f;

#pragma unroll
    for (int it = 0; it < HCH_ / (256 * 4); it++) {   // 4 float4 iterations
        int base = pix0 + (it * 256 + tid) * 4;
        float4 a0 = *(const float4*)(p0p + base);
        float4 a1 = *(const float4*)(p1p + base);
        float4 a3 = *(const float4*)(p3p + base);
        int4 in4 = *(const int4*)(insp + base);
        float v0[4] = {a0.x, a0.y, a0.z, a0.w};
        float v1[4] = {a1.x, a1.y, a1.z, a1.w};
        float v3[4] = {a3.x, a3.y, a3.z, a3.w};
        int ii[4] = {in4.x, in4.y, in4.z, in4.w};
#pragma unroll
        for (int j = 0; j < 4; j++) {
            int pix = base + j;
            float sex = ftanh_(v0[j]) + (float)(pix & (W_ - 1)) * (2.0f / 2047.0f);
            float sey = ftanh_(v1[j]) + (float)(pix >> 10) * (1.0f / 1023.0f);
            float seed = fsigmoid_(v3[j]);
            int ins = ii[j];
#pragma unroll
            for (int k = 0; k < K_; k++) {
                if (prs[k]) {
                    float dx = sex - cx[k];
                    float dy = sey - cy[k];
                    float dist = __expf(-sxp[k] * (dx * dx + dy * dy));
                    bool fg = (ins == k + 1);
                    // err_bg=2d, err_fg=2-2d; bin=floor(err*(M/2)) via one cvt:
                    int ib = (int)fminf(128.0f * dist, 127.0f);
                    int bin = fg ? 127 - ib : ib;
                    atomicAdd(hpriv + (k * MP_ + bin), fg ? 0x10001u : 1u);
                    if (fg) { float d = seed - dist; sfg[k] += d * d; }
                }
            }
        }
    }
    __syncthreads();

    unsigned int* gp = partial + (size_t)blockIdx.x * KM_;
    for (int i = tid; i < KM_; i += 256) {
        int r = (i >> 7) * MP_ + (i & (M_ - 1));
        gp[i] = hsh[0][r] + hsh[1][r] + hsh[2][r] + hsh[3][r];
    }

    // seed_fg: wave shfl reduce -> cross-wave LDS -> plain store
#pragma unroll
    for (int k = 0; k < K_; k++) {
        float v = sfg[k];
#pragma unroll
        for (int off = 32; off; off >>= 1) v += __shfl_down(v, off, 64);
        sfg[k] = v;
    }
    if ((tid & 63) == 0) {
        int w = tid >> 6;
#pragma unroll
        for (int k = 0; k < K_; k++) xfg[w][k] = sfg[k];
    }
    __syncthreads();
    if (tid < K_)
        sfgpart[(size_t)(b * K_ + tid) * HBPB_ + blk] =
            xfg[0][tid] + xfg[1][tid] + xfg[2][tid] + xfg[3][tid];
}

// ---- Stage 3: fused partial-reduce + Lovasz suffix scan + seed_fg + out add ----
// 32 blocks x 1024 threads: 8 groups x 128 bins; each group sums 16 partials.
// loss = binw*[0.5*J_0 + sum_{j>=1} J_j], J_j = 1-(p-F_j)/(p+R_j-F_j).
// R11: 128-bin suffix scan + Jaccard + reduce in wave 0 registers (u64-packed
// {n,f}, 2 bins/lane, 6 shfl steps); seed_fg reduce concurrent on waves 4-5.
__global__ __launch_bounds__(1024) void lovasz_kernel(const unsigned int* __restrict__ partial,
                                                      const float* __restrict__ sfgpart,
                                                      const float* __restrict__ wsf,
                                                      float* __restrict__ out) {
    int bk = blockIdx.x;
    int b = bk >> 3, k = bk & 7;
    int tid = threadIdx.x;
    int bin = tid & (M_ - 1), grp = tid >> 7;   // grp 0..7
    constexpr int PER = HBPB_ / 8;              // 16 partials per group

    const unsigned int* p = partial +
        (size_t)(b * HBPB_ + grp * PER) * KM_ + k * M_ + bin;
    unsigned int n = 0, f = 0;
#pragma unroll
    for (int j = 0; j < PER; j++) {             // coalesced: 128 lanes x 4B per j
        unsigned int v = p[(size_t)j * KM_];
        n += v & 0xffffu;
        f += v >> 16;
    }

    __shared__ unsigned int gn[8][M_], gf[8][M_];
    __shared__ float lovp;
    __shared__ float xs[2];
    gn[grp][bin] = n; gf[grp][bin] = f;
    __syncthreads();

    float pcnt = wsf[CNT_OFF + bk];
    float pp = fmaxf(pcnt, 1.0f);

    if (tid < 64) {
        // wave 0: lane l owns bins 2l and 2l+1. Pack n in hi32, f in lo32
        // (suffix sums < 2^31 each, so no cross-field carry).
        unsigned long long p0 = 0ull, p1 = 0ull;
#pragma unroll
        for (int g = 0; g < 8; g++) {
            uint2 vn = *(const uint2*)&gn[g][2 * tid];
            uint2 vf = *(const uint2*)&gf[g][2 * tid];
            p0 += ((unsigned long long)vn.x << 32) | (unsigned long long)vf.x;
            p1 += ((unsigned long long)vn.y << 32) | (unsigned long long)vf.y;
        }
        // inclusive suffix scan over lane pair-sums (Hillis-Steele, 6 steps)
        unsigned long long T = p0 + p1;
#pragma unroll
        for (int off = 1; off < 64; off <<= 1) {
            unsigned long long t = __shfl_down(T, off, 64);
            if (tid + off < 64) T += t;
        }
        unsigned long long S0 = T;          // suffix from bin 2l
        unsigned long long S1 = T - p0;     // suffix from bin 2l+1
        float acc;
        {
            unsigned int R = (unsigned int)(S0 >> 32), F = (unsigned int)S0;
            float J = (R == 0) ? 0.0f : (1.0f - (pp - (float)F) / (pp + (float)(R - F)));
            acc = (tid == 0 ? 0.5f : 1.0f) * J;
        }
        {
            unsigned int R = (unsigned int)(S1 >> 32), F = (unsigned int)S1;
            float J = (R == 0) ? 0.0f : (1.0f - (pp - (float)F) / (pp + (float)(R - F)));
            acc += J;
        }
#pragma unroll
        for (int off = 32; off; off >>= 1) acc += __shfl_down(acc, off, 64);
        if (tid == 0) lovp = acc;
    } else if (tid >= 256 && tid < 384) {
        // waves 4-5 (concurrent with wave 0): seed_fg total, 128 partials
        float sv = sfgpart[(size_t)bk * HBPB_ + (tid - 256)];
#pragma unroll
        for (int off = 32; off; off >>= 1) sv += __shfl_down(sv, off, 64);
        if ((tid & 63) == 0) xs[(tid - 256) >> 6] = sv;
    }
    __syncthreads();

    if (tid == 0 && pcnt > 0.0f) {
        float lov = lovp * (2.0f / (float)M_);
        float sfgt = xs[0] + xs[1];
        float objf = wsf[OBJF_OFF + b];
        atomicAdd(out, (lov / objf + sfgt / (float)N_) * (1.0f / (float)B_));
    }
}

extern "C" void kernel_launch(void* const* d_in, const int* in_sizes, int n_in,
                              void* d_out, int out_size, void* d_ws, size_t ws_size,
                              hipStream_t stream) {
    const float* pred = (const float*)d_in[0];
    const int* inst = (const int*)d_in[1];
    const int* lab = (const int*)d_in[2];
    float* out = (float*)d_out;

    unsigned int* partial = (unsigned int*)d_ws;
    float* sfgpart = (float*)((char*)d_ws + SFG_OFF_B);
    float* pstat = (float*)((char*)d_ws + PSTAT_OFF_B);
    float* wsf = (float*)((char*)d_ws + WSF_OFF_B);

    // 3 dispatches; no memset (stats zeroes out[0]; ws fully overwritten).
    // NOTE: cooperative single-dispatch fusion measured 2.6x WORSE (R10) —
    // grid.sync on gfx950 forces cross-XCD L2 writeback/invalidate (~100us/sync).
    // NOTE: 4th dispatch (separate finalize) measured +6.3us total (R12) —
    // dispatch overhead ~5-6us each; keep at 3.
    stats_kernel<<<SB_, 256, 0, stream>>>(pred, inst, lab, pstat, out);
    hist_kernel<<<HB_, 256, 0, stream>>>(pred, inst, pstat, wsf, partial, sfgpart, out);
    lovasz_kernel<<<BK_, 1024, 0, stream>>>(partial, sfgpart, wsf, out);
}